// Round 11
// baseline (333.550 us; speedup 1.0000x reference)
//
#include <hip/hip_runtime.h>
#include <hip/hip_bf16.h>
#include <stdint.h>

#define N_NODES  50000
#define N_GRAPHS 256
#define DIM      128
#define N_EDGES  800000
#define K2       256            // fused K = [agg | h]
#define N_STRIPS (N_NODES / 16) // 3125, exact
#define PAD_CAP  64             // max degree slack (mean 16; fixed edge list, no overflow)
#define AGG_LD   132            // sAgg row stride in ushorts (264B: 4-way instead of 16-way LDS conflict)

typedef __attribute__((ext_vector_type(8))) short  short8;
typedef __attribute__((ext_vector_type(4))) short  s4v;
typedef __attribute__((ext_vector_type(4))) float  floatx4;
typedef __attribute__((ext_vector_type(4))) int    intx4;

__device__ __forceinline__ ushort f2bf(float f) {
    union { float f; uint32_t u; } c; c.f = f;
    uint32_t u = c.u;
    return (ushort)((u + 0x7fffu + ((u >> 16) & 1u)) >> 16);  // RNE
}

// ---------- fused prep: convert_x | prep_w | gbounds | cnt-zero | out-zero ----------
#define MB_CONV 6250
#define MB_PREPW (MB_CONV + 384)
#define MB_GB   (MB_PREPW + 196)
#define MB_CNT  (MB_GB + 196)
#define MB_OUT  (MB_CNT + 256)
__global__ __launch_bounds__(256) void k_misc(const float* __restrict__ x, ushort* __restrict__ xb,
                                              const float* __restrict__ Wl0, const float* __restrict__ Wr0,
                                              const float* __restrict__ Wl1, const float* __restrict__ Wr1,
                                              const float* __restrict__ Wl2, const float* __restrict__ Wr2,
                                              ushort* __restrict__ Wt,
                                              const int* __restrict__ batch,
                                              int* __restrict__ gstart, int* __restrict__ gend,
                                              int* __restrict__ cnt, float* __restrict__ out) {
    int b = blockIdx.x, t = threadIdx.x;
    if (b < MB_CONV) {                       // fp32 x -> bf16 (float4 granularity)
        int i = b * 256 + t;                 // i < 1.6M exactly
        float4 v = ((const float4*)x)[i];
        uint32_t lo = (uint32_t)f2bf(v.x) | ((uint32_t)f2bf(v.y) << 16);
        uint32_t hi = (uint32_t)f2bf(v.z) | ((uint32_t)f2bf(v.w) << 16);
        ((uint2*)xb)[i] = make_uint2(lo, hi);
    } else if (b < MB_PREPW) {               // Wt[l][n][k] = bf16(k<128 ? Wl[k][n] : Wr[k-128][n])
        int i = (b - MB_CONV) * 256 + t;     // i < 98304 exactly
        int layer = i / (DIM * K2);
        int j = i % (DIM * K2);
        int n = j / K2, k = j % K2;
        const float* Wl = (layer == 0) ? Wl0 : (layer == 1) ? Wl1 : Wl2;
        const float* Wr = (layer == 0) ? Wr0 : (layer == 1) ? Wr1 : Wr2;
        float v = (k < DIM) ? Wl[k * DIM + n] : Wr[(k - DIM) * DIM + n];
        Wt[i] = f2bf(v);
    } else if (b < MB_GB) {                  // per-graph node ranges from sorted batch
        int i = (b - MB_PREPW) * 256 + t;
        if (i < N_NODES) {
            int g = batch[i];
            if (i == 0) gstart[g] = 0;
            int gn = (i + 1 < N_NODES) ? batch[i + 1] : -1;
            if (gn != g) {
                gend[g] = i + 1;
                if (gn >= 0) gstart[gn] = i + 1;
            }
        }
    } else if (b < MB_CNT) {                 // zero degree counters (pre-build)
        int i = (b - MB_GB) * 256 + t;
        if (i < N_NODES) cnt[i] = 0;
    } else {                                 // zero output (pre-readout atomics)
        int i = (b - MB_CNT) * 256 + t;
        if (i < N_GRAPHS * 2 * DIM) out[i] = 0.f;
    }
}

// ---------- direct adjacency build: one kernel, global atomics ----------
// Insertion order is nondeterministic; k_layer<0> sorts each list before any use.
__global__ __launch_bounds__(256) void k_build_direct(const int* __restrict__ src,
                                                      const int* __restrict__ dst,
                                                      int* __restrict__ cnt,
                                                      int* __restrict__ padded) {
    int i = blockIdx.x * 256 + threadIdx.x;
    if (i < N_EDGES) {
        int d = dst[i], s = src[i];
        int p = atomicAdd(&cnt[d], 1);
        if (p < PAD_CAP) padded[(size_t)d * PAD_CAP + p] = s;
    }
}

// ---------- fused SAGE layer (4 waves, 4 nodes/wave, 2-chunk dbuf; PAIRED-ROW gather) ----------
// Gather now loads 2 rows per instruction: lanes 0-31 take edge e0+2g, lanes 32-63 take
// e0+2g+1, 8B (dwordx2) per lane -> 8 VMEM instructions per 16-edge chunk instead of 16,
// at identical cache-line count. Each lane accumulates 4 dims of its half's edges; one
// shfl_xor(32) per node at finalize merges the halves. Tests whether the gather is
// TA/TCP instruction-rate-bound (helps) or line-service-bound (null).
// MODE 0: in-wave bitonic sort + canonical writeback. MODE 1: plain bf16 out.
// MODE 2: LDS f32 tile + in-block per-graph mean/max readout.
template <int MODE>
__global__ __launch_bounds__(256) void k_layer(const ushort* __restrict__ h_in,
                                               int* __restrict__ padded,
                                               const int* __restrict__ cnt,
                                               const ushort* __restrict__ Wt,
                                               const float* __restrict__ bias,
                                               ushort* __restrict__ out_bf,
                                               const int* __restrict__ batch,
                                               float* __restrict__ gout) {
    __shared__ alignas(16) ushort sAgg[16 * AGG_LD];   // 4.1 KB (padded stride)
    __shared__ int    sIdx[16 * PAD_CAP];          // 4 KB neighbor lists
    __shared__ int    sCnt[16];
    __shared__ int    sChl[4][17];                 // per-wave chunk list: q | (e0<<8)
    __shared__ int    sNch[4];
    __shared__ int    sGb[(MODE == 2) ? 16 : 1];   // per-row graph ids (MODE 2)
    __shared__ float  hTile[(MODE == 2) ? 16 * DIM : 1];  // 8 KB f32 out tile (MODE 2)

    int t    = threadIdx.x;
    int wid  = t >> 6;
    int lane = t & 63;
    int half = lane >> 5;                          // 0: even edge of pair, 1: odd
    int l5   = lane & 31;                          // dims [4*l5, 4*l5+4)
    int r0   = blockIdx.x * 16;
    const uint2* hw2 = (const uint2*)h_in;         // 32 uint2 per 256B row

    // ---- stage neighbor lists + degrees (coalesced) ----
    ((intx4*)sIdx)[t] = ((const intx4*)(padded + (size_t)r0 * PAD_CAP))[t];
    if (t < 16) sCnt[t] = cnt[r0 + t];
    if (MODE == 2 && t >= 16 && t < 32) sGb[t - 16] = batch[r0 + t - 16];
    __syncthreads();

    // ---- MODE 0: canonicalize lists in-wave (4 sequential 64-lane bitonics) ----
    if (MODE == 0) {
        #pragma unroll
        for (int q = 0; q < 4; ++q) {
            int nl  = wid * 4 + q;
            int m   = min(sCnt[nl], PAD_CAP);
            int* lst = sIdx + nl * PAD_CAP;
            int v = (lane < m) ? lst[lane] : 0x7fffffff;   // pads sort to the end
            #pragma unroll
            for (int k = 2; k <= 64; k <<= 1) {
                #pragma unroll
                for (int j = k >> 1; j > 0; j >>= 1) {
                    int other  = __shfl_xor(v, j, 64);
                    bool down  = (lane & k) != 0;
                    bool lower = (lane & j) == 0;
                    v = (lower ^ down) ? min(v, other) : max(v, other);
                }
            }
            if (lane < m) {
                lst[lane] = v;                             // wave-local LDS, no barrier
                padded[(size_t)(r0 + nl) * PAD_CAP + lane] = v;  // canonical for layers 1-2
            }
        }
    }

    // ---- per-wave flattened chunk list (wave-uniform; lane 0 writes) ----
    if (lane == 0) {
        int n = 0;
        #pragma unroll
        for (int q = 0; q < 4; ++q) {
            int m = min(sCnt[wid * 4 + q], PAD_CAP);
            for (int e0 = 0; e0 < m; e0 += 16)
                sChl[wid][n++] = q | (e0 << 8);
        }
        sNch[wid] = n;
    }
    // zero agg rows for isolated nodes (no chunks emitted for them)
    #pragma unroll
    for (int q = 0; q < 4; ++q) {
        int node = wid * 4 + q;
        if (sCnt[node] == 0) ((uint32_t*)(sAgg + node * AGG_LD))[lane] = 0u;
    }
    int nch = sNch[wid];

    // per-lane accumulators: 4 dims x 2 ILP banks (this lane's half of the edges)
    float a0[2] = {0.f, 0.f}, a1[2] = {0.f, 0.f};
    float a2[2] = {0.f, 0.f}, a3[2] = {0.f, 0.f};
    uint2 va[8], vb[8];                            // double-buffered paired-row chunks

    auto issue = [&](int ci, uint2 (&v)[8]) {
        int ch   = sChl[wid][ci];
        int q    = ch & 255, e0 = ch >> 8;
        int node = wid * 4 + q;
        int m    = min(sCnt[node], PAD_CAP);
        const int* lst = sIdx + node * PAD_CAP;
        #pragma unroll
        for (int g = 0; g < 8; ++g) {
            int ek = e0 + 2 * g + half;
            int id = lst[ek < m ? ek : m - 1];     // LDS broadcast (2 addrs/wave); m>=1 here
            v[g] = hw2[(size_t)id * 32 + l5];      // dwordx2: 2 rows per instruction
        }
    };
    auto consume = [&](int ci, uint2 (&v)[8], bool isLast) {
        int ch   = sChl[wid][ci];
        int q    = ch & 255, e0 = ch >> 8;
        int node = wid * 4 + q;
        int deg  = sCnt[node];
        int m    = min(deg, PAD_CAP);
        #pragma unroll
        for (int g = 0; g < 8; ++g) {
            bool in = (e0 + 2 * g + half) < m;     // predicated tail (bf16 +0.0)
            uint32_t wx = in ? v[g].x : 0u;
            uint32_t wy = in ? v[g].y : 0u;
            int b = g & 1;
            a0[b] += __uint_as_float(wx << 16);
            a1[b] += __uint_as_float(wx & 0xffff0000u);
            a2[b] += __uint_as_float(wy << 16);
            a3[b] += __uint_as_float(wy & 0xffff0000u);
        }
        bool lastOfNode = isLast || ((sChl[wid][ci + 1] & 255) != q);
        if (lastOfNode) {
            float t0 = a0[0] + a0[1], t1 = a1[0] + a1[1];
            float t2 = a2[0] + a2[1], t3 = a3[0] + a3[1];
            t0 += __shfl_xor(t0, 32, 64);          // merge even/odd edge halves
            t1 += __shfl_xor(t1, 32, 64);
            t2 += __shfl_xor(t2, 32, 64);
            t3 += __shfl_xor(t3, 32, 64);
            float inv = 1.0f / (float)(deg > 0 ? deg : 1);
            if (lane < 32) {                       // 32 lanes x 8B = full 256B agg row
                uint2 o;
                o.x = (uint32_t)f2bf(t0 * inv) | ((uint32_t)f2bf(t1 * inv) << 16);
                o.y = (uint32_t)f2bf(t2 * inv) | ((uint32_t)f2bf(t3 * inv) << 16);
                *((uint2*)(sAgg + node * AGG_LD) + l5) = o;
            }
            a0[0] = a0[1] = a1[0] = a1[1] = 0.f;
            a2[0] = a2[1] = a3[0] = a3[1] = 0.f;
        }
    };

    if (nch > 0) {
        issue(0, va);
        int i = 0;
        while (true) {
            bool hasB = (i + 1) < nch;
            if (hasB) issue(i + 1, vb);            // overlap: loads(i+1) || accumulate(i)
            consume(i, va, !hasB);
            if (!hasB) break;
            bool hasA = (i + 2) < nch;
            if (hasA) issue(i + 2, va);
            consume(i + 1, vb, !hasA);
            if (!hasA) break;
            i += 2;
        }
    }
    __syncthreads();

    // ---- phase 2: MFMA. A-frags: lane holds A[m=lane&15][k=quad*8+j] ----
    int row  = lane & 15;
    int quad = lane >> 4;
    short8 a[8];
    const ushort* srow = sAgg + row * AGG_LD + quad * 8;   // 8B-aligned (264B row stride)
    #pragma unroll
    for (int ks = 0; ks < 4; ++ks) {               // 2x ds_read_b64 per frag (4-way max)
        s4v lo = *(const s4v*)(srow + ks * 32);
        s4v hi = *(const s4v*)(srow + ks * 32 + 4);
        short8 v = {lo[0], lo[1], lo[2], lo[3], hi[0], hi[1], hi[2], hi[3]};
        a[ks] = v;
    }
    const ushort* hrow = h_in + (size_t)(r0 + row) * DIM + quad * 8;
    #pragma unroll
    for (int ks = 0; ks < 4; ++ks) a[4 + ks] = *(const short8*)(hrow + ks * 32);

    #pragma unroll
    for (int c = 0; c < 2; ++c) {
        int ct  = wid * 2 + c;                     // 4 waves x 2 = 8 col-tiles
        int col = ct * 16 + row;
        const ushort* wrow = Wt + (size_t)col * K2 + quad * 8;
        floatx4 acc = {0.f, 0.f, 0.f, 0.f};
        #pragma unroll
        for (int ks = 0; ks < 8; ++ks) {
            short8 b = *(const short8*)(wrow + ks * 32);
            acc = __builtin_amdgcn_mfma_f32_16x16x32_bf16(a[ks], b, acc, 0, 0, 0);
        }
        float bv = bias[col];
        #pragma unroll
        for (int r = 0; r < 4; ++r) {
            int m = r0 + quad * 4 + r;             // C/D: col=lane&15, row=quad*4+reg
            float v = acc[r] + bv;
            v = v > 0.f ? v : 0.f;
            if (MODE < 2) out_bf[(size_t)m * DIM + col] = f2bf(v);   // cached: next layer gathers it
            else          hTile[(quad * 4 + r) * DIM + col] = v;
        }
    }

    // ---- MODE 2: in-block mean/max readout (batch sorted -> run-length flush) ----
    if (MODE == 2) {
        __syncthreads();
        int d     = t & 127;
        bool doMax = t >= 128;                     // threads 0-127: sum; 128-255: max
        float s = 0.f, mx = 0.f;
        int cur = sGb[0];
        #pragma unroll
        for (int m = 0; m < 16; ++m) {
            int g = sGb[m];
            if (g != cur) {
                if (doMax) atomicMax((int*)&gout[cur * 2 * DIM + DIM + d], __float_as_int(mx));
                else       atomicAdd(&gout[cur * 2 * DIM + d], s);
                cur = g; s = 0.f; mx = 0.f;
            }
            float v = hTile[m * DIM + d];
            s += v; mx = fmaxf(mx, v);
        }
        if (doMax) atomicMax((int*)&gout[cur * 2 * DIM + DIM + d], __float_as_int(mx));
        else       atomicAdd(&gout[cur * 2 * DIM + d], s);
    }
}

__global__ __launch_bounds__(256) void k_finalize(float* __restrict__ out,
                                                  const int* __restrict__ gstart,
                                                  const int* __restrict__ gend) {
    int i = blockIdx.x * 256 + threadIdx.x;
    if (i < N_GRAPHS * DIM) {
        int g = i / DIM, d = i % DIM;
        int c = gend[g] - gstart[g];
        out[g * 2 * DIM + d] /= (float)(c > 0 ? c : 1);
    }
}

extern "C" void kernel_launch(void* const* d_in, const int* in_sizes, int n_in,
                              void* d_out, int out_size, void* d_ws, size_t ws_size,
                              hipStream_t stream) {
    const float* x     = (const float*)d_in[0];
    const int*   ei    = (const int*)d_in[1];
    const int*   src   = ei;
    const int*   dst   = ei + N_EDGES;
    const int*   batch = (const int*)d_in[2];
    const float* Wl[3] = {(const float*)d_in[3], (const float*)d_in[6], (const float*)d_in[9]};
    const float* bl[3] = {(const float*)d_in[4], (const float*)d_in[7], (const float*)d_in[10]};
    const float* Wr[3] = {(const float*)d_in[5], (const float*)d_in[8], (const float*)d_in[11]};
    float* out = (float*)d_out;

    char* base = (char*)d_ws;
    size_t o = 0;
    auto alloc = [&](size_t b) -> char* {
        char* p = base + o;
        o = (o + b + 255) & ~(size_t)255;
        return p;
    };
    int*     gstart = (int*)alloc((size_t)N_GRAPHS * 4);
    int*     gend   = (int*)alloc((size_t)N_GRAPHS * 4);
    int*     cnt    = (int*)alloc((size_t)N_NODES * 4);
    int*     padded = (int*)alloc((size_t)N_NODES * PAD_CAP * 4);    // 12.8 MB
    ushort*  xb     = (ushort*)alloc((size_t)N_NODES * DIM * 2);
    ushort*  ha     = (ushort*)alloc((size_t)N_NODES * DIM * 2);
    ushort*  hb     = (ushort*)alloc((size_t)N_NODES * DIM * 2);
    ushort*  Wt     = (ushort*)alloc((size_t)3 * DIM * K2 * 2);
    (void)ws_size; (void)n_in; (void)in_sizes; (void)out_size;

    // 6 dispatches total
    k_misc<<<MB_OUT, 256, 0, stream>>>(x, xb, Wl[0], Wr[0], Wl[1], Wr[1], Wl[2], Wr[2],
                                       Wt, batch, gstart, gend, cnt, out);
    k_build_direct<<<(N_EDGES + 255) / 256, 256, 0, stream>>>(src, dst, cnt, padded);

    k_layer<0><<<N_STRIPS, 256, 0, stream>>>(xb, padded, cnt, Wt,                bl[0], ha, batch, out);
    k_layer<1><<<N_STRIPS, 256, 0, stream>>>(ha, padded, cnt, Wt + DIM * K2,     bl[1], hb, batch, out);
    k_layer<2><<<N_STRIPS, 256, 0, stream>>>(hb, padded, cnt, Wt + 2 * DIM * K2, bl[2], nullptr, batch, out);

    k_finalize<<<(N_GRAPHS * DIM + 255) / 256, 256, 0, stream>>>(out, gstart, gend);
}

// Round 12
// 319.127 us; speedup vs baseline: 1.0452x; 1.0452x over previous
//
#include <hip/hip_runtime.h>
#include <hip/hip_bf16.h>
#include <stdint.h>

#define N_NODES  50000
#define N_GRAPHS 256
#define DIM      128
#define N_EDGES  800000
#define K2       256            // fused K = [agg | h]
#define N_STRIPS (N_NODES / 16) // 3125, exact
#define PAD_CAP  64             // max degree slack (mean 16; fixed edge list, no overflow)
#define AGG_LD   132            // sAgg row stride in ushorts (264B: 4-way instead of 16-way LDS conflict)

typedef __attribute__((ext_vector_type(8))) short  short8;
typedef __attribute__((ext_vector_type(4))) short  s4v;
typedef __attribute__((ext_vector_type(4))) float  floatx4;

__device__ __forceinline__ ushort f2bf(float f) {
    union { float f; uint32_t u; } c; c.f = f;
    uint32_t u = c.u;
    return (ushort)((u + 0x7fffu + ((u >> 16) & 1u)) >> 16);  // RNE
}

// ---------- fused prep: convert_x | prep_w | gbounds | cnt-zero | out-zero ----------
#define MB_CONV 6250
#define MB_PREPW (MB_CONV + 384)
#define MB_GB   (MB_PREPW + 196)
#define MB_CNT  (MB_GB + 196)
#define MB_OUT  (MB_CNT + 256)
__global__ __launch_bounds__(256) void k_misc(const float* __restrict__ x, ushort* __restrict__ xb,
                                              const float* __restrict__ Wl0, const float* __restrict__ Wr0,
                                              const float* __restrict__ Wl1, const float* __restrict__ Wr1,
                                              const float* __restrict__ Wl2, const float* __restrict__ Wr2,
                                              ushort* __restrict__ Wt,
                                              const int* __restrict__ batch,
                                              int* __restrict__ gstart, int* __restrict__ gend,
                                              int* __restrict__ cnt, float* __restrict__ out) {
    int b = blockIdx.x, t = threadIdx.x;
    if (b < MB_CONV) {                       // fp32 x -> bf16 (float4 granularity)
        int i = b * 256 + t;                 // i < 1.6M exactly
        float4 v = ((const float4*)x)[i];
        uint32_t lo = (uint32_t)f2bf(v.x) | ((uint32_t)f2bf(v.y) << 16);
        uint32_t hi = (uint32_t)f2bf(v.z) | ((uint32_t)f2bf(v.w) << 16);
        ((uint2*)xb)[i] = make_uint2(lo, hi);
    } else if (b < MB_PREPW) {               // Wt[l][n][k] = bf16(k<128 ? Wl[k][n] : Wr[k-128][n])
        int i = (b - MB_CONV) * 256 + t;     // i < 98304 exactly
        int layer = i / (DIM * K2);
        int j = i % (DIM * K2);
        int n = j / K2, k = j % K2;
        const float* Wl = (layer == 0) ? Wl0 : (layer == 1) ? Wl1 : Wl2;
        const float* Wr = (layer == 0) ? Wr0 : (layer == 1) ? Wr1 : Wr2;
        float v = (k < DIM) ? Wl[k * DIM + n] : Wr[(k - DIM) * DIM + n];
        Wt[i] = f2bf(v);
    } else if (b < MB_GB) {                  // per-graph node ranges from sorted batch
        int i = (b - MB_PREPW) * 256 + t;
        if (i < N_NODES) {
            int g = batch[i];
            if (i == 0) gstart[g] = 0;
            int gn = (i + 1 < N_NODES) ? batch[i + 1] : -1;
            if (gn != g) {
                gend[g] = i + 1;
                if (gn >= 0) gstart[gn] = i + 1;
            }
        }
    } else if (b < MB_CNT) {                 // zero degree counters (pre-build)
        int i = (b - MB_GB) * 256 + t;
        if (i < N_NODES) cnt[i] = 0;
    } else {                                 // zero output (pre-readout atomics)
        int i = (b - MB_CNT) * 256 + t;
        if (i < N_GRAPHS * 2 * DIM) out[i] = 0.f;
    }
}

// ---------- direct adjacency build: one kernel, global atomics ----------
// Insertion order is nondeterministic; k_layer<0> sorts each list before any use.
// padded is USHORT (src < 2^16): halves the random-scatter line footprint (12.8->6.4MB)
// and every later list read.
__global__ __launch_bounds__(256) void k_build_direct(const int* __restrict__ src,
                                                      const int* __restrict__ dst,
                                                      int* __restrict__ cnt,
                                                      ushort* __restrict__ padded) {
    int i = blockIdx.x * 256 + threadIdx.x;
    if (i < N_EDGES) {
        int d = dst[i], s = src[i];
        int p = atomicAdd(&cnt[d], 1);
        if (p < PAD_CAP) padded[(size_t)d * PAD_CAP + p] = (ushort)s;
    }
}

// ---------- fused SAGE layer (R10 gather: 4 waves, 4 nodes/wave, 2-chunk reg dbuf) ----------
// MODE 0: in-wave bitonic sort of each list + canonical writeback for layers 1-2.
// MODE 1: plain middle layer (bf16 out). MODE 2: last layer; LDS f32 tile + in-block
// per-graph mean/max readout. sAgg stride AGG_LD=132 + b64 A-frag reads: 0 LDS conflicts
// (verified R10). Lists are ushort (2KB LDS).
template <int MODE>
__global__ __launch_bounds__(256) void k_layer(const ushort* __restrict__ h_in,
                                               ushort* __restrict__ padded,
                                               const int* __restrict__ cnt,
                                               const ushort* __restrict__ Wt,
                                               const float* __restrict__ bias,
                                               ushort* __restrict__ out_bf,
                                               const int* __restrict__ batch,
                                               float* __restrict__ gout) {
    __shared__ alignas(16) ushort sAgg[16 * AGG_LD];   // 4.1 KB (padded stride)
    __shared__ alignas(16) ushort sIdx[16 * PAD_CAP];  // 2 KB neighbor lists (ushort ids)
    __shared__ int    sCnt[16];
    __shared__ int    sChl[4][17];                 // per-wave chunk list: q | (e0<<8)
    __shared__ int    sNch[4];
    __shared__ int    sGb[(MODE == 2) ? 16 : 1];   // per-row graph ids (MODE 2)
    __shared__ float  hTile[(MODE == 2) ? 16 * DIM : 1];  // 8 KB f32 out tile (MODE 2)

    int t    = threadIdx.x;
    int wid  = t >> 6;
    int lane = t & 63;
    int r0   = blockIdx.x * 16;
    const uint32_t* hw = (const uint32_t*)h_in;    // 64 dwords per row

    // ---- stage neighbor lists + degrees (coalesced: 256 threads x 8B = 2 KB) ----
    ((uint2*)sIdx)[t] = ((const uint2*)(padded + (size_t)r0 * PAD_CAP))[t];
    if (t < 16) sCnt[t] = cnt[r0 + t];
    if (MODE == 2 && t >= 16 && t < 32) sGb[t - 16] = batch[r0 + t - 16];
    __syncthreads();

    // ---- MODE 0: canonicalize lists in-wave (4 sequential 64-lane bitonics) ----
    if (MODE == 0) {
        #pragma unroll
        for (int q = 0; q < 4; ++q) {
            int nl  = wid * 4 + q;
            int m   = min(sCnt[nl], PAD_CAP);
            ushort* lst = sIdx + nl * PAD_CAP;
            int v = (lane < m) ? (int)lst[lane] : 0xFFFF;  // pads sort to the end (>49999)
            #pragma unroll
            for (int k = 2; k <= 64; k <<= 1) {
                #pragma unroll
                for (int j = k >> 1; j > 0; j >>= 1) {
                    int other  = __shfl_xor(v, j, 64);
                    bool down  = (lane & k) != 0;
                    bool lower = (lane & j) == 0;
                    v = (lower ^ down) ? min(v, other) : max(v, other);
                }
            }
            if (lane < m) {
                lst[lane] = (ushort)v;                     // wave-local LDS, no barrier
                padded[(size_t)(r0 + nl) * PAD_CAP + lane] = (ushort)v;  // canonical for layers 1-2
            }
        }
    }

    // ---- per-wave flattened chunk list (wave-uniform; lane 0 writes) ----
    if (lane == 0) {
        int n = 0;
        #pragma unroll
        for (int q = 0; q < 4; ++q) {
            int m = min(sCnt[wid * 4 + q], PAD_CAP);
            for (int e0 = 0; e0 < m; e0 += 16)
                sChl[wid][n++] = q | (e0 << 8);
        }
        sNch[wid] = n;
    }
    // zero agg rows for isolated nodes (no chunks emitted for them)
    #pragma unroll
    for (int q = 0; q < 4; ++q) {
        int node = wid * 4 + q;
        if (sCnt[node] == 0) ((uint32_t*)(sAgg + node * AGG_LD))[lane] = 0u;
    }
    int nch = sNch[wid];

    float ax[4] = {0.f, 0.f, 0.f, 0.f};
    float ay[4] = {0.f, 0.f, 0.f, 0.f};
    uint32_t va[16], vb[16];                       // double-buffered gather rows

    auto issue = [&](int ci, uint32_t (&v)[16]) {
        int ch   = sChl[wid][ci];
        int q    = ch & 255, e0 = ch >> 8;
        int node = wid * 4 + q;
        int m    = min(sCnt[node], PAD_CAP);
        const ushort* lst = sIdx + node * PAD_CAP;
        #pragma unroll
        for (int k = 0; k < 16; ++k) {
            int ek = e0 + k;
            int id = (int)lst[ek < m ? ek : m - 1];  // LDS broadcast; m>=1 here
            v[k] = hw[(size_t)id * 64 + lane];       // 16 row loads in flight
        }
    };
    auto consume = [&](int ci, uint32_t (&v)[16], bool isLast) {
        int ch   = sChl[wid][ci];
        int q    = ch & 255, e0 = ch >> 8;
        int node = wid * 4 + q;
        int deg  = sCnt[node];
        int m    = min(deg, PAD_CAP);
        #pragma unroll
        for (int k = 0; k < 16; ++k) {
            uint32_t w = (e0 + k < m) ? v[k] : 0u; // predicated tail (bf16 +0.0)
            ax[k & 3] += __uint_as_float(w << 16);
            ay[k & 3] += __uint_as_float(w & 0xffff0000u);
        }
        bool lastOfNode = isLast || ((sChl[wid][ci + 1] & 255) != q);
        if (lastOfNode) {
            float axs = (ax[0] + ax[1]) + (ax[2] + ax[3]);
            float ays = (ay[0] + ay[1]) + (ay[2] + ay[3]);
            float inv = 1.0f / (float)(deg > 0 ? deg : 1);
            uint32_t o = (uint32_t)f2bf(axs * inv) | ((uint32_t)f2bf(ays * inv) << 16);
            ((uint32_t*)(sAgg + node * AGG_LD))[lane] = o;
            #pragma unroll
            for (int j = 0; j < 4; ++j) { ax[j] = 0.f; ay[j] = 0.f; }
        }
    };

    if (nch > 0) {
        issue(0, va);
        int i = 0;
        while (true) {
            bool hasB = (i + 1) < nch;
            if (hasB) issue(i + 1, vb);            // overlap: loads(i+1) || accumulate(i)
            consume(i, va, !hasB);
            if (!hasB) break;
            bool hasA = (i + 2) < nch;
            if (hasA) issue(i + 2, va);
            consume(i + 1, vb, !hasA);
            if (!hasA) break;
            i += 2;
        }
    }
    __syncthreads();

    // ---- phase 2: MFMA. A-frags: lane holds A[m=lane&15][k=quad*8+j] ----
    int row  = lane & 15;
    int quad = lane >> 4;
    short8 a[8];
    const ushort* srow = sAgg + row * AGG_LD + quad * 8;   // 8B-aligned (264B row stride)
    #pragma unroll
    for (int ks = 0; ks < 4; ++ks) {               // 2x ds_read_b64 per frag (4-way max)
        s4v lo = *(const s4v*)(srow + ks * 32);
        s4v hi = *(const s4v*)(srow + ks * 32 + 4);
        short8 v = {lo[0], lo[1], lo[2], lo[3], hi[0], hi[1], hi[2], hi[3]};
        a[ks] = v;
    }
    const ushort* hrow = h_in + (size_t)(r0 + row) * DIM + quad * 8;
    #pragma unroll
    for (int ks = 0; ks < 4; ++ks) a[4 + ks] = *(const short8*)(hrow + ks * 32);

    #pragma unroll
    for (int c = 0; c < 2; ++c) {
        int ct  = wid * 2 + c;                     // 4 waves x 2 = 8 col-tiles
        int col = ct * 16 + row;
        const ushort* wrow = Wt + (size_t)col * K2 + quad * 8;
        floatx4 acc = {0.f, 0.f, 0.f, 0.f};
        #pragma unroll
        for (int ks = 0; ks < 8; ++ks) {
            short8 b = *(const short8*)(wrow + ks * 32);
            acc = __builtin_amdgcn_mfma_f32_16x16x32_bf16(a[ks], b, acc, 0, 0, 0);
        }
        float bv = bias[col];
        #pragma unroll
        for (int r = 0; r < 4; ++r) {
            int m = r0 + quad * 4 + r;             // C/D: col=lane&15, row=quad*4+reg
            float v = acc[r] + bv;
            v = v > 0.f ? v : 0.f;
            if (MODE < 2) out_bf[(size_t)m * DIM + col] = f2bf(v);   // cached: next layer gathers it
            else          hTile[(quad * 4 + r) * DIM + col] = v;
        }
    }

    // ---- MODE 2: in-block mean/max readout (batch sorted -> run-length flush) ----
    if (MODE == 2) {
        __syncthreads();
        int d     = t & 127;
        bool doMax = t >= 128;                     // threads 0-127: sum; 128-255: max
        float s = 0.f, mx = 0.f;
        int cur = sGb[0];
        #pragma unroll
        for (int m = 0; m < 16; ++m) {
            int g = sGb[m];
            if (g != cur) {
                if (doMax) atomicMax((int*)&gout[cur * 2 * DIM + DIM + d], __float_as_int(mx));
                else       atomicAdd(&gout[cur * 2 * DIM + d], s);
                cur = g; s = 0.f; mx = 0.f;
            }
            float v = hTile[m * DIM + d];
            s += v; mx = fmaxf(mx, v);
        }
        if (doMax) atomicMax((int*)&gout[cur * 2 * DIM + DIM + d], __float_as_int(mx));
        else       atomicAdd(&gout[cur * 2 * DIM + d], s);
    }
}

__global__ __launch_bounds__(256) void k_finalize(float* __restrict__ out,
                                                  const int* __restrict__ gstart,
                                                  const int* __restrict__ gend) {
    int i = blockIdx.x * 256 + threadIdx.x;
    if (i < N_GRAPHS * DIM) {
        int g = i / DIM, d = i % DIM;
        int c = gend[g] - gstart[g];
        out[g * 2 * DIM + d] /= (float)(c > 0 ? c : 1);
    }
}

extern "C" void kernel_launch(void* const* d_in, const int* in_sizes, int n_in,
                              void* d_out, int out_size, void* d_ws, size_t ws_size,
                              hipStream_t stream) {
    const float* x     = (const float*)d_in[0];
    const int*   ei    = (const int*)d_in[1];
    const int*   src   = ei;
    const int*   dst   = ei + N_EDGES;
    const int*   batch = (const int*)d_in[2];
    const float* Wl[3] = {(const float*)d_in[3], (const float*)d_in[6], (const float*)d_in[9]};
    const float* bl[3] = {(const float*)d_in[4], (const float*)d_in[7], (const float*)d_in[10]};
    const float* Wr[3] = {(const float*)d_in[5], (const float*)d_in[8], (const float*)d_in[11]};
    float* out = (float*)d_out;

    char* base = (char*)d_ws;
    size_t o = 0;
    auto alloc = [&](size_t b) -> char* {
        char* p = base + o;
        o = (o + b + 255) & ~(size_t)255;
        return p;
    };
    int*     gstart = (int*)alloc((size_t)N_GRAPHS * 4);
    int*     gend   = (int*)alloc((size_t)N_GRAPHS * 4);
    int*     cnt    = (int*)alloc((size_t)N_NODES * 4);
    ushort*  padded = (ushort*)alloc((size_t)N_NODES * PAD_CAP * 2);  // 6.4 MB (ushort ids)
    ushort*  xb     = (ushort*)alloc((size_t)N_NODES * DIM * 2);
    ushort*  ha     = (ushort*)alloc((size_t)N_NODES * DIM * 2);
    ushort*  hb     = (ushort*)alloc((size_t)N_NODES * DIM * 2);
    ushort*  Wt     = (ushort*)alloc((size_t)3 * DIM * K2 * 2);
    (void)ws_size; (void)n_in; (void)in_sizes; (void)out_size;

    // 6 dispatches total
    k_misc<<<MB_OUT, 256, 0, stream>>>(x, xb, Wl[0], Wr[0], Wl[1], Wr[1], Wl[2], Wr[2],
                                       Wt, batch, gstart, gend, cnt, out);
    k_build_direct<<<(N_EDGES + 255) / 256, 256, 0, stream>>>(src, dst, cnt, padded);

    k_layer<0><<<N_STRIPS, 256, 0, stream>>>(xb, padded, cnt, Wt,                bl[0], ha, batch, out);
    k_layer<1><<<N_STRIPS, 256, 0, stream>>>(ha, padded, cnt, Wt + DIM * K2,     bl[1], hb, batch, out);
    k_layer<2><<<N_STRIPS, 256, 0, stream>>>(hb, padded, cnt, Wt + 2 * DIM * K2, bl[2], nullptr, batch, out);

    k_finalize<<<(N_GRAPHS * DIM + 255) / 256, 256, 0, stream>>>(out, gstart, gend);
}

// Round 13
// 312.826 us; speedup vs baseline: 1.0662x; 1.0201x over previous
//
#include <hip/hip_runtime.h>
#include <hip/hip_bf16.h>
#include <stdint.h>

#define N_NODES  50000
#define N_GRAPHS 256
#define DIM      128
#define N_EDGES  800000
#define K2       256            // fused K = [agg | h]
#define N_STRIPS (N_NODES / 16) // 3125, exact
#define PAD_CAP  64             // max degree slack (mean 16; fixed edge list, no overflow)
#define AGG_LD   132            // sAgg row stride in ushorts (264B: 4-way instead of 16-way LDS conflict)

typedef __attribute__((ext_vector_type(8))) short  short8;
typedef __attribute__((ext_vector_type(4))) short  s4v;
typedef __attribute__((ext_vector_type(4))) float  floatx4;

__device__ __forceinline__ ushort f2bf(float f) {
    union { float f; uint32_t u; } c; c.f = f;
    uint32_t u = c.u;
    return (ushort)((u + 0x7fffu + ((u >> 16) & 1u)) >> 16);  // RNE
}

// ---------- fused prep: build | convert_x | prep_w | gbounds | out-zero ----------
// Build blocks take the LOW blockIdx range: they dispatch first, and their atomic/
// scatter latency overlaps the streaming conversion blocks that follow (disjoint
// resources: LSU-latency vs HBM BW). cnt is zeroed by a preceding hipMemsetAsync
// (intra-kernel block order is undefined, so the zero cannot live in this kernel).
#define PB_BUILD 3125                       // 3125*256 = 800000 edges exactly
#define PB_CONV  (PB_BUILD + 6250)          // 6250*256 float4 = 1.6M exactly
#define PB_PREPW (PB_CONV + 384)            // 384*256 = 98304 = 3*DIM*K2 exactly
#define PB_GB    (PB_PREPW + 196)
#define PB_OUT   (PB_GB + 256)
__global__ __launch_bounds__(256) void k_prep(const int* __restrict__ src, const int* __restrict__ dst,
                                              int* __restrict__ cnt, ushort* __restrict__ padded,
                                              const float* __restrict__ x, ushort* __restrict__ xb,
                                              const float* __restrict__ Wl0, const float* __restrict__ Wr0,
                                              const float* __restrict__ Wl1, const float* __restrict__ Wr1,
                                              const float* __restrict__ Wl2, const float* __restrict__ Wr2,
                                              ushort* __restrict__ Wt,
                                              const int* __restrict__ batch,
                                              int* __restrict__ gstart, int* __restrict__ gend,
                                              float* __restrict__ out) {
    int b = blockIdx.x, t = threadIdx.x;
    if (b < PB_BUILD) {                      // adjacency build: global atomics + scatter.
        int i = b * 256 + t;                 // insertion order nondeterministic; k_layer<0>
        int d = dst[i], s = src[i];          // sorts each list before any use.
        int p = atomicAdd(&cnt[d], 1);
        if (p < PAD_CAP) padded[(size_t)d * PAD_CAP + p] = (ushort)s;
    } else if (b < PB_CONV) {                // fp32 x -> bf16 (float4 granularity)
        int i = (b - PB_BUILD) * 256 + t;
        float4 v = ((const float4*)x)[i];
        uint32_t lo = (uint32_t)f2bf(v.x) | ((uint32_t)f2bf(v.y) << 16);
        uint32_t hi = (uint32_t)f2bf(v.z) | ((uint32_t)f2bf(v.w) << 16);
        ((uint2*)xb)[i] = make_uint2(lo, hi);
    } else if (b < PB_PREPW) {               // Wt[l][n][k] = bf16(k<128 ? Wl[k][n] : Wr[k-128][n])
        int i = (b - PB_CONV) * 256 + t;
        int layer = i / (DIM * K2);
        int j = i % (DIM * K2);
        int n = j / K2, k = j % K2;
        const float* Wl = (layer == 0) ? Wl0 : (layer == 1) ? Wl1 : Wl2;
        const float* Wr = (layer == 0) ? Wr0 : (layer == 1) ? Wr1 : Wr2;
        float v = (k < DIM) ? Wl[k * DIM + n] : Wr[(k - DIM) * DIM + n];
        Wt[i] = f2bf(v);
    } else if (b < PB_GB) {                  // per-graph node ranges from sorted batch
        int i = (b - PB_PREPW) * 256 + t;
        if (i < N_NODES) {
            int g = batch[i];
            if (i == 0) gstart[g] = 0;
            int gn = (i + 1 < N_NODES) ? batch[i + 1] : -1;
            if (gn != g) {
                gend[g] = i + 1;
                if (gn >= 0) gstart[gn] = i + 1;
            }
        }
    } else {                                 // zero output (pre-readout atomics)
        int i = (b - PB_GB) * 256 + t;
        if (i < N_GRAPHS * 2 * DIM) out[i] = 0.f;
    }
}

// ---------- fused SAGE layer (R12 best-known: 4 waves, 4 nodes/wave, 2-chunk reg dbuf) ----------
// MODE 0: in-wave bitonic sort of each list + canonical writeback for layers 1-2.
// MODE 1: plain middle layer (bf16 out). MODE 2: last layer; LDS f32 tile + in-block
// per-graph mean/max readout. sAgg stride AGG_LD=132 + b64 A-frag reads: 0 LDS conflicts
// (verified R10). Lists are ushort (2KB LDS; 6.4MB global footprint).
template <int MODE>
__global__ __launch_bounds__(256) void k_layer(const ushort* __restrict__ h_in,
                                               ushort* __restrict__ padded,
                                               const int* __restrict__ cnt,
                                               const ushort* __restrict__ Wt,
                                               const float* __restrict__ bias,
                                               ushort* __restrict__ out_bf,
                                               const int* __restrict__ batch,
                                               float* __restrict__ gout) {
    __shared__ alignas(16) ushort sAgg[16 * AGG_LD];   // 4.1 KB (padded stride)
    __shared__ alignas(16) ushort sIdx[16 * PAD_CAP];  // 2 KB neighbor lists (ushort ids)
    __shared__ int    sCnt[16];
    __shared__ int    sChl[4][17];                 // per-wave chunk list: q | (e0<<8)
    __shared__ int    sNch[4];
    __shared__ int    sGb[(MODE == 2) ? 16 : 1];   // per-row graph ids (MODE 2)
    __shared__ float  hTile[(MODE == 2) ? 16 * DIM : 1];  // 8 KB f32 out tile (MODE 2)

    int t    = threadIdx.x;
    int wid  = t >> 6;
    int lane = t & 63;
    int r0   = blockIdx.x * 16;
    const uint32_t* hw = (const uint32_t*)h_in;    // 64 dwords per row

    // ---- stage neighbor lists + degrees (coalesced: 256 threads x 8B = 2 KB) ----
    ((uint2*)sIdx)[t] = ((const uint2*)(padded + (size_t)r0 * PAD_CAP))[t];
    if (t < 16) sCnt[t] = cnt[r0 + t];
    if (MODE == 2 && t >= 16 && t < 32) sGb[t - 16] = batch[r0 + t - 16];
    __syncthreads();

    // ---- MODE 0: canonicalize lists in-wave (4 sequential 64-lane bitonics) ----
    if (MODE == 0) {
        #pragma unroll
        for (int q = 0; q < 4; ++q) {
            int nl  = wid * 4 + q;
            int m   = min(sCnt[nl], PAD_CAP);
            ushort* lst = sIdx + nl * PAD_CAP;
            int v = (lane < m) ? (int)lst[lane] : 0xFFFF;  // pads sort to the end (>49999)
            #pragma unroll
            for (int k = 2; k <= 64; k <<= 1) {
                #pragma unroll
                for (int j = k >> 1; j > 0; j >>= 1) {
                    int other  = __shfl_xor(v, j, 64);
                    bool down  = (lane & k) != 0;
                    bool lower = (lane & j) == 0;
                    v = (lower ^ down) ? min(v, other) : max(v, other);
                }
            }
            if (lane < m) {
                lst[lane] = (ushort)v;                     // wave-local LDS, no barrier
                padded[(size_t)(r0 + nl) * PAD_CAP + lane] = (ushort)v;  // canonical for layers 1-2
            }
        }
    }

    // ---- per-wave flattened chunk list (wave-uniform; lane 0 writes) ----
    if (lane == 0) {
        int n = 0;
        #pragma unroll
        for (int q = 0; q < 4; ++q) {
            int m = min(sCnt[wid * 4 + q], PAD_CAP);
            for (int e0 = 0; e0 < m; e0 += 16)
                sChl[wid][n++] = q | (e0 << 8);
        }
        sNch[wid] = n;
    }
    // zero agg rows for isolated nodes (no chunks emitted for them)
    #pragma unroll
    for (int q = 0; q < 4; ++q) {
        int node = wid * 4 + q;
        if (sCnt[node] == 0) ((uint32_t*)(sAgg + node * AGG_LD))[lane] = 0u;
    }
    int nch = sNch[wid];

    float ax[4] = {0.f, 0.f, 0.f, 0.f};
    float ay[4] = {0.f, 0.f, 0.f, 0.f};
    uint32_t va[16], vb[16];                       // double-buffered gather rows

    auto issue = [&](int ci, uint32_t (&v)[16]) {
        int ch   = sChl[wid][ci];
        int q    = ch & 255, e0 = ch >> 8;
        int node = wid * 4 + q;
        int m    = min(sCnt[node], PAD_CAP);
        const ushort* lst = sIdx + node * PAD_CAP;
        #pragma unroll
        for (int k = 0; k < 16; ++k) {
            int ek = e0 + k;
            int id = (int)lst[ek < m ? ek : m - 1];  // LDS broadcast; m>=1 here
            v[k] = hw[(size_t)id * 64 + lane];       // 16 row loads in flight
        }
    };
    auto consume = [&](int ci, uint32_t (&v)[16], bool isLast) {
        int ch   = sChl[wid][ci];
        int q    = ch & 255, e0 = ch >> 8;
        int node = wid * 4 + q;
        int deg  = sCnt[node];
        int m    = min(deg, PAD_CAP);
        #pragma unroll
        for (int k = 0; k < 16; ++k) {
            uint32_t w = (e0 + k < m) ? v[k] : 0u; // predicated tail (bf16 +0.0)
            ax[k & 3] += __uint_as_float(w << 16);
            ay[k & 3] += __uint_as_float(w & 0xffff0000u);
        }
        bool lastOfNode = isLast || ((sChl[wid][ci + 1] & 255) != q);
        if (lastOfNode) {
            float axs = (ax[0] + ax[1]) + (ax[2] + ax[3]);
            float ays = (ay[0] + ay[1]) + (ay[2] + ay[3]);
            float inv = 1.0f / (float)(deg > 0 ? deg : 1);
            uint32_t o = (uint32_t)f2bf(axs * inv) | ((uint32_t)f2bf(ays * inv) << 16);
            ((uint32_t*)(sAgg + node * AGG_LD))[lane] = o;
            #pragma unroll
            for (int j = 0; j < 4; ++j) { ax[j] = 0.f; ay[j] = 0.f; }
        }
    };

    if (nch > 0) {
        issue(0, va);
        int i = 0;
        while (true) {
            bool hasB = (i + 1) < nch;
            if (hasB) issue(i + 1, vb);            // overlap: loads(i+1) || accumulate(i)
            consume(i, va, !hasB);
            if (!hasB) break;
            bool hasA = (i + 2) < nch;
            if (hasA) issue(i + 2, va);
            consume(i + 1, vb, !hasA);
            if (!hasA) break;
            i += 2;
        }
    }
    __syncthreads();

    // ---- phase 2: MFMA. A-frags: lane holds A[m=lane&15][k=quad*8+j] ----
    int row  = lane & 15;
    int quad = lane >> 4;
    short8 a[8];
    const ushort* srow = sAgg + row * AGG_LD + quad * 8;   // 8B-aligned (264B row stride)
    #pragma unroll
    for (int ks = 0; ks < 4; ++ks) {               // 2x ds_read_b64 per frag (4-way max)
        s4v lo = *(const s4v*)(srow + ks * 32);
        s4v hi = *(const s4v*)(srow + ks * 32 + 4);
        short8 v = {lo[0], lo[1], lo[2], lo[3], hi[0], hi[1], hi[2], hi[3]};
        a[ks] = v;
    }
    const ushort* hrow = h_in + (size_t)(r0 + row) * DIM + quad * 8;
    #pragma unroll
    for (int ks = 0; ks < 4; ++ks) a[4 + ks] = *(const short8*)(hrow + ks * 32);

    #pragma unroll
    for (int c = 0; c < 2; ++c) {
        int ct  = wid * 2 + c;                     // 4 waves x 2 = 8 col-tiles
        int col = ct * 16 + row;
        const ushort* wrow = Wt + (size_t)col * K2 + quad * 8;
        floatx4 acc = {0.f, 0.f, 0.f, 0.f};
        #pragma unroll
        for (int ks = 0; ks < 8; ++ks) {
            short8 b = *(const short8*)(wrow + ks * 32);
            acc = __builtin_amdgcn_mfma_f32_16x16x32_bf16(a[ks], b, acc, 0, 0, 0);
        }
        float bv = bias[col];
        #pragma unroll
        for (int r = 0; r < 4; ++r) {
            int m = r0 + quad * 4 + r;             // C/D: col=lane&15, row=quad*4+reg
            float v = acc[r] + bv;
            v = v > 0.f ? v : 0.f;
            if (MODE < 2) out_bf[(size_t)m * DIM + col] = f2bf(v);   // cached: next layer gathers it
            else          hTile[(quad * 4 + r) * DIM + col] = v;
        }
    }

    // ---- MODE 2: in-block mean/max readout (batch sorted -> run-length flush) ----
    if (MODE == 2) {
        __syncthreads();
        int d     = t & 127;
        bool doMax = t >= 128;                     // threads 0-127: sum; 128-255: max
        float s = 0.f, mx = 0.f;
        int cur = sGb[0];
        #pragma unroll
        for (int m = 0; m < 16; ++m) {
            int g = sGb[m];
            if (g != cur) {
                if (doMax) atomicMax((int*)&gout[cur * 2 * DIM + DIM + d], __float_as_int(mx));
                else       atomicAdd(&gout[cur * 2 * DIM + d], s);
                cur = g; s = 0.f; mx = 0.f;
            }
            float v = hTile[m * DIM + d];
            s += v; mx = fmaxf(mx, v);
        }
        if (doMax) atomicMax((int*)&gout[cur * 2 * DIM + DIM + d], __float_as_int(mx));
        else       atomicAdd(&gout[cur * 2 * DIM + d], s);
    }
}

__global__ __launch_bounds__(256) void k_finalize(float* __restrict__ out,
                                                  const int* __restrict__ gstart,
                                                  const int* __restrict__ gend) {
    int i = blockIdx.x * 256 + threadIdx.x;
    if (i < N_GRAPHS * DIM) {
        int g = i / DIM, d = i % DIM;
        int c = gend[g] - gstart[g];
        out[g * 2 * DIM + d] /= (float)(c > 0 ? c : 1);
    }
}

extern "C" void kernel_launch(void* const* d_in, const int* in_sizes, int n_in,
                              void* d_out, int out_size, void* d_ws, size_t ws_size,
                              hipStream_t stream) {
    const float* x     = (const float*)d_in[0];
    const int*   ei    = (const int*)d_in[1];
    const int*   src   = ei;
    const int*   dst   = ei + N_EDGES;
    const int*   batch = (const int*)d_in[2];
    const float* Wl[3] = {(const float*)d_in[3], (const float*)d_in[6], (const float*)d_in[9]};
    const float* bl[3] = {(const float*)d_in[4], (const float*)d_in[7], (const float*)d_in[10]};
    const float* Wr[3] = {(const float*)d_in[5], (const float*)d_in[8], (const float*)d_in[11]};
    float* out = (float*)d_out;

    char* base = (char*)d_ws;
    size_t o = 0;
    auto alloc = [&](size_t b) -> char* {
        char* p = base + o;
        o = (o + b + 255) & ~(size_t)255;
        return p;
    };
    int*     gstart = (int*)alloc((size_t)N_GRAPHS * 4);
    int*     gend   = (int*)alloc((size_t)N_GRAPHS * 4);
    int*     cnt    = (int*)alloc((size_t)N_NODES * 4);
    ushort*  padded = (ushort*)alloc((size_t)N_NODES * PAD_CAP * 2);  // 6.4 MB (ushort ids)
    ushort*  xb     = (ushort*)alloc((size_t)N_NODES * DIM * 2);
    ushort*  ha     = (ushort*)alloc((size_t)N_NODES * DIM * 2);
    ushort*  hb     = (ushort*)alloc((size_t)N_NODES * DIM * 2);
    ushort*  Wt     = (ushort*)alloc((size_t)3 * DIM * K2 * 2);
    (void)ws_size; (void)n_in; (void)in_sizes; (void)out_size;

    // 6 dispatches: memset(cnt) | prep(build||conv||weights||gbounds||outzero) | 3 layers | finalize
    hipMemsetAsync(cnt, 0, (size_t)N_NODES * 4, stream);
    k_prep<<<PB_OUT, 256, 0, stream>>>(src, dst, cnt, padded, x, xb,
                                       Wl[0], Wr[0], Wl[1], Wr[1], Wl[2], Wr[2],
                                       Wt, batch, gstart, gend, out);

    k_layer<0><<<N_STRIPS, 256, 0, stream>>>(xb, padded, cnt, Wt,                bl[0], ha, batch, out);
    k_layer<1><<<N_STRIPS, 256, 0, stream>>>(ha, padded, cnt, Wt + DIM * K2,     bl[1], hb, batch, out);
    k_layer<2><<<N_STRIPS, 256, 0, stream>>>(hb, padded, cnt, Wt + 2 * DIM * K2, bl[2], nullptr, batch, out);

    k_finalize<<<(N_GRAPHS * DIM + 255) / 256, 256, 0, stream>>>(out, gstart, gend);
}